// Round 8
// baseline (719.072 us; speedup 1.0000x reference)
//
#include <hip/hip_runtime.h>
#include <hip/hip_bf16.h>

#define B_  64
#define T_  512
#define V_  512
#define E_  128
#define D_  256
#define D2_ 512

typedef unsigned short u16;
typedef unsigned int   u32;
typedef short s16x8 __attribute__((ext_vector_type(8)));
typedef _Float16 f16x8 __attribute__((ext_vector_type(8)));
typedef float f32x4 __attribute__((ext_vector_type(4)));
typedef unsigned short u16x2 __attribute__((ext_vector_type(2)));
typedef unsigned short u16x4 __attribute__((ext_vector_type(4)));

__device__ __forceinline__ float bf2f(u16 u){
    union { u32 i; float f; } c; c.i = ((u32)u) << 16; return c.f;
}
__device__ __forceinline__ u16 f2bf(float f){
    union { float f; u32 i; } c; c.f = f;
    u32 u = c.i;
    return (u16)((u + 0x7fffu + ((u >> 16) & 1u)) >> 16);
}
__device__ __forceinline__ u16 f2h(float f){
    union { _Float16 h; u16 u; } c; c.h = (_Float16)f; return c.u;
}
// tanh for bounded args (|x| <~ 20): 1 - 2/(e^{2x}+1).
__device__ __forceinline__ float tanh_b(float x){
    float e = __expf(2.0f * x);
    return fmaf(-2.0f, __builtin_amdgcn_rcpf(e + 1.0f), 1.0f);
}
// Workgroup barrier that only drains LDS (lgkm) — leaves global loads/stores
// in flight. Safe when cross-wave communication is LDS-only.
__device__ __forceinline__ void barrier_lgkm(){
    asm volatile("s_waitcnt lgkmcnt(0)\n\ts_barrier" ::: "memory");
}

// ---------------------------------------------------------------------------
// K1: EW[v,d] = sum_e embed[v,e] * W_ih[e,d] + b_h[d]   (512 x 256, fp32 exact)
// ---------------------------------------------------------------------------
__global__ __launch_bounds__(256) void k_ew(const float* __restrict__ embed,
                                            const float* __restrict__ W_ih,
                                            const float* __restrict__ b_h,
                                            float* __restrict__ EW){
    __shared__ float er[E_];
    int v = blockIdx.x;
    int tid = threadIdx.x;
    if (tid < E_) er[tid] = embed[v*E_ + tid];
    __syncthreads();
    float acc = b_h[tid];
    #pragma unroll 4
    for (int e = 0; e < E_; ++e) acc += er[e] * W_ih[e*D_ + tid];
    EW[v*D_ + tid] = acc;
}

// ---------------------------------------------------------------------------
// K1b: XP[t*64+b][d] = EW[x[b][t]][d]  (fp32, 32 MB; aliases EP/EQ region)
// ---------------------------------------------------------------------------
__global__ __launch_bounds__(256) void k_gather(const int* __restrict__ x,
                                                const float* __restrict__ EW,
                                                float* __restrict__ XP){
    int m = blockIdx.x * 4 + (threadIdx.x >> 6);   // row index t*64+b
    int lane = threadIdx.x & 63;
    int b = m & 63, t = m >> 6;
    int v = x[b*T_ + t];
    float4 val = *(const float4*)&EW[v*D_ + lane*4];
    *(float4*)&XP[(size_t)m*D_ + lane*4] = val;
}

// ---------------------------------------------------------------------------
// K1c: single launch converting all three weight matrices to bf16 transposed:
//   i in [0, 65536):          Wab[n*256+k] = bf16(W_att[k*256+n])
//   i in [65536, 131072):     Uab[...]     = bf16(U_att[...])
//   i in [131072, 393216):    fcWb[n*512+k]= bf16(fc_W[k*512+n])
// ---------------------------------------------------------------------------
__global__ __launch_bounds__(256) void k_cvt3(const float* __restrict__ W_att,
                                              const float* __restrict__ U_att,
                                              const float* __restrict__ fc_W,
                                              u16* __restrict__ Wab,
                                              u16* __restrict__ Uab,
                                              u16* __restrict__ fcWb){
    int i = blockIdx.x * 256 + threadIdx.x;
    if (i < 65536){
        int n = i >> 8, k = i & 255;
        Wab[i] = f2bf(W_att[k*D_ + n]);
    } else if (i < 131072){
        int j = i - 65536;
        int n = j >> 8, k = j & 255;
        Uab[j] = f2bf(U_att[k*D_ + n]);
    } else {
        int j = i - 131072;
        int n = j >> 9, k = j & 511;
        fcWb[j] = f2bf(fc_W[k*V_ + n]);
    }
}

// ---------------------------------------------------------------------------
// K2: sequential h-chain. 16 blocks x 4 batches (M=4), 512 threads (8 waves,
// 2/SIMD). Single fp16 MFMA pass (round 5: 260 us).
// v6: accumulators split into k-halves -> 4 independent MFMA chains per wave
// (accA over ks 0..3, accB over ks 4..7; summed scalar in the tail). Tests
// whether part of the 354 cyc/step over the 621-cyc issue floor is MFMA
// dependent-chain latency (2 chains x 2 waves may under-fill the pipe).
// ---------------------------------------------------------------------------
__global__ __launch_bounds__(512, 2) void k_rnn(const float* __restrict__ XP,
                                                const float* __restrict__ W_hh,
                                                u16* __restrict__ HC){
    __shared__ u16 hf[2][4][272];   // fp16 bits of h, double-buffered
    int tid  = threadIdx.x;
    int lane = tid & 63;
    int w    = tid >> 6;          // wave 0..7: n-range w*32..w*32+31
    int col  = lane & 15;
    int colA = col & 3;           // A-row alias (rows 4..15 duplicate 0..3)
    int quad = lane >> 4;
    int bb0  = blockIdx.x * 4;

    // Preload W_hh B-fragments (fp16): k = ks*32+quad*8+j, n = w*32+nt*16+col
    f16x8 bfh[2][8];
    #pragma unroll
    for (int nt = 0; nt < 2; ++nt){
        int n = w*32 + nt*16 + col;
        #pragma unroll
        for (int ks = 0; ks < 8; ++ks){
            f16x8 th;
            #pragma unroll
            for (int j = 0; j < 8; ++j){
                int k = ks*32 + quad*8 + j;
                th[j] = (_Float16)W_hh[k*D_ + n];
            }
            bfh[nt][ks] = th;
        }
    }
    for (int i = tid; i < 2*4*272; i += 512) (&hf[0][0][0])[i] = 0;

    // stepped base pointers (advance by one t-slab per step)
    const float* p  = XP + (size_t)bb0*D_ + w*32 + col;       // + r*D_ + nt*16
    u16*         hc = HC + (size_t)bb0*D2_ + w*32 + col;      // + r*D2_ + nt*16

    float ewv[2][4];
    #pragma unroll
    for (int nt = 0; nt < 2; ++nt)
        #pragma unroll
        for (int r = 0; r < 4; ++r)
            ewv[nt][r] = p[r*D_ + nt*16];   // all lanes (quads duplicate)
    p += (size_t)B_*D_;
    __syncthreads();

    for (int t = 0; t < T_; ++t){
        int rb = t & 1, wb = rb ^ 1;
        f32x4 accA[2], accB[2];
        #pragma unroll
        for (int nt = 0; nt < 2; ++nt)
            #pragma unroll
            for (int r = 0; r < 4; ++r){ accA[nt][r] = ewv[nt][r]; accB[nt][r] = 0.0f; }

        // bulk-load all A-fragments for this step (8 ds_read_b128, pipelined)
        f16x8 ah[8];
        #pragma unroll
        for (int ks = 0; ks < 8; ++ks)
            ah[ks] = *(const f16x8*)&hf[rb][colA][ks*32 + quad*8];

        // prefetch next step's xp (stays in flight across raw barrier)
        if (t + 1 < T_){
            #pragma unroll
            for (int nt = 0; nt < 2; ++nt)
                #pragma unroll
                for (int r = 0; r < 4; ++r)
                    ewv[nt][r] = p[r*D_ + nt*16];
        }
        p += (size_t)B_*D_;

        #pragma unroll
        for (int ks = 0; ks < 4; ++ks){
            accA[0] = __builtin_amdgcn_mfma_f32_16x16x32_f16(ah[ks],   bfh[0][ks],   accA[0], 0, 0, 0);
            accA[1] = __builtin_amdgcn_mfma_f32_16x16x32_f16(ah[ks],   bfh[1][ks],   accA[1], 0, 0, 0);
            accB[0] = __builtin_amdgcn_mfma_f32_16x16x32_f16(ah[ks+4], bfh[0][ks+4], accB[0], 0, 0, 0);
            accB[1] = __builtin_amdgcn_mfma_f32_16x16x32_f16(ah[ks+4], bfh[1][ks+4], accB[1], 0, 0, 0);
        }

        // tail: lane owns (r = quad, nt = 0..1); static extracts via cndmask
        #pragma unroll
        for (int nt = 0; nt < 2; ++nt){
            f32x4 sA = accA[nt], sB = accB[nt];
            float vA = (quad & 2) ? ((quad & 1) ? sA[3] : sA[2])
                                  : ((quad & 1) ? sA[1] : sA[0]);
            float vB = (quad & 2) ? ((quad & 1) ? sB[3] : sB[2])
                                  : ((quad & 1) ? sB[1] : sB[0]);
            float h  = tanh_b(vA + vB);
            int n    = w*32 + nt*16 + col;
            hf[wb][quad][n]      = f2h(h);    // fp16 for the recurrence
            hc[quad*D2_ + nt*16] = f2bf(h);   // bf16 for downstream (unchanged)
        }
        hc += (size_t)B_*D2_;
        barrier_lgkm();   // h_t LDS visible; HC stores/XP loads stay in flight
    }
}

// ---------------------------------------------------------------------------
// Generic MFMA GEMM: out[M=32768, N] = A[M,K](bf16, lda) @ Wb[N,K](bf16).
// mode 2: out bf16 = exp(2*acc)  (for EP/EQ).
// mode 3: out bf16 = exp(2*acc), N=512 over [Wab|Uab]: n<256 -> EP[m*256+n],
//         n>=256 -> EQ[m*256+n-256] (EQ = EP + 32768*256, contiguous).
// LDS stride 88 u16 = 44 dw (12 mod 32): balanced 8 lanes/bank-group.
// ---------------------------------------------------------------------------
__global__ __launch_bounds__(256) void k_gemm(const u16* __restrict__ A, int lda,
                                              const u16* __restrict__ Wb,
                                              const float* __restrict__ bias,
                                              void* __restrict__ out,
                                              int K, int N, int mode){
    __shared__ u16 As[64][88];
    __shared__ u16 Ws[64][88];
    int tid  = threadIdx.x;
    int lane = tid & 63;
    int w    = tid >> 6;
    int col  = lane & 15;
    int quad = lane >> 4;
    int m0   = blockIdx.x * 64;
    int n0   = blockIdx.y * 64;

    f32x4 acc[4];
    #pragma unroll
    for (int nt = 0; nt < 4; ++nt)
        #pragma unroll
        for (int r = 0; r < 4; ++r) acc[nt][r] = 0.0f;

    for (int kk = 0; kk < K; kk += 64){
        #pragma unroll
        for (int i = 0; i < 2; ++i){
            int idx = tid + i*256;        // 0..511
            int r   = idx >> 3;           // row 0..63
            int c8  = (idx & 7) * 8;      // k-oct
            *(s16x8*)&As[r][c8] = *(const s16x8*)&A [(size_t)(m0 + r)*lda + kk + c8];
            *(s16x8*)&Ws[r][c8] = *(const s16x8*)&Wb[(size_t)(n0 + r)*K   + kk + c8];
        }
        barrier_lgkm();
        #pragma unroll
        for (int ks = 0; ks < 2; ++ks){
            s16x8 a = *(const s16x8*)&As[w*16 + col][ks*32 + quad*8];
            #pragma unroll
            for (int nt = 0; nt < 4; ++nt){
                s16x8 b = *(const s16x8*)&Ws[nt*16 + col][ks*32 + quad*8];
                acc[nt] = __builtin_amdgcn_mfma_f32_16x16x32_bf16(a, b, acc[nt], 0, 0, 0);
            }
        }
        barrier_lgkm();
    }
    #pragma unroll
    for (int nt = 0; nt < 4; ++nt){
        int n = n0 + nt*16 + col;
        float bv = (mode == 1 && bias) ? bias[n] : 0.0f;
        #pragma unroll
        for (int r = 0; r < 4; ++r){
            int m = m0 + w*16 + quad*4 + r;
            float v = acc[nt][r] + bv;
            if (mode == 1){
                int b = m & 63, t = m >> 6;
                ((float*)out)[(size_t)(b*T_ + t)*V_ + n] = v;
            } else if (mode == 2){
                ((u16*)out)[(size_t)m*N + n] = f2bf(__expf(2.0f * v));
            } else if (mode == 3){
                u16* dst = (u16*)out + ((size_t)(n >> 8)) * ((size_t)32768 * 256);
                dst[(size_t)m*256 + (n & 255)] = f2bf(__expf(2.0f * v));
            } else {
                ((u16*)out)[(size_t)m*N + n] = f2bf(v);
            }
        }
    }
}

// ---------------------------------------------------------------------------
// K4b: final fc layer, 128x128x64 tile (512 thr, 8 waves as 2Mx4N).
// ---------------------------------------------------------------------------
__global__ __launch_bounds__(512) void k_fc(const u16* __restrict__ A,
                                            const u16* __restrict__ Wb,
                                            const float* __restrict__ bias,
                                            float* __restrict__ out){
    __shared__ u16 As[128][88];
    __shared__ u16 Ws[128][88];
    int tid  = threadIdx.x;
    int lane = tid & 63;
    int w    = tid >> 6;        // 8 waves
    int wm   = w >> 2;          // 0..1: M-half
    int wn   = w & 3;           // 0..3: N-quarter
    int col  = lane & 15;
    int quad = lane >> 4;
    int m0   = blockIdx.x * 128;
    int n0   = blockIdx.y * 128;

    f32x4 acc[4][2];
    #pragma unroll
    for (int mt = 0; mt < 4; ++mt)
        #pragma unroll
        for (int nt = 0; nt < 2; ++nt)
            #pragma unroll
            for (int r = 0; r < 4; ++r) acc[mt][nt][r] = 0.0f;

    for (int kk = 0; kk < D2_; kk += 64){
        #pragma unroll
        for (int i = 0; i < 2; ++i){
            int idx = tid + i*512;        // 0..1023
            int r   = idx >> 3;           // row 0..127
            int c8  = (idx & 7) * 8;
            *(s16x8*)&As[r][c8] = *(const s16x8*)&A [(size_t)(m0 + r)*D2_ + kk + c8];
            *(s16x8*)&Ws[r][c8] = *(const s16x8*)&Wb[(size_t)(n0 + r)*D2_ + kk + c8];
        }
        barrier_lgkm();
        #pragma unroll
        for (int ks = 0; ks < 2; ++ks){
            s16x8 b0 = *(const s16x8*)&Ws[wn*32 +      col][ks*32 + quad*8];
            s16x8 b1 = *(const s16x8*)&Ws[wn*32 + 16 + col][ks*32 + quad*8];
            #pragma unroll
            for (int mt = 0; mt < 4; ++mt){
                s16x8 a = *(const s16x8*)&As[wm*64 + mt*16 + col][ks*32 + quad*8];
                acc[mt][0] = __builtin_amdgcn_mfma_f32_16x16x32_bf16(a, b0, acc[mt][0], 0, 0, 0);
                acc[mt][1] = __builtin_amdgcn_mfma_f32_16x16x32_bf16(a, b1, acc[mt][1], 0, 0, 0);
            }
        }
        barrier_lgkm();
    }
    #pragma unroll
    for (int nt = 0; nt < 2; ++nt){
        int n = n0 + wn*32 + nt*16 + col;
        float bv = bias[n];
        #pragma unroll
        for (int mt = 0; mt < 4; ++mt){
            #pragma unroll
            for (int r = 0; r < 4; ++r){
                int m = m0 + wm*64 + mt*16 + quad*4 + r;
                int b = m & 63, t = m >> 6;
                out[(size_t)(b*T_ + t)*V_ + n] = acc[mt][nt][r] + bv;
            }
        }
    }
}

// ---------------------------------------------------------------------------
// K5: energies. v2: block = (b, tm, pt), tile = 64 t-rows x 32 tp, d=256.
// Thread (tg = tid>>3, dg = tid&7) owns TWO t-rows (t0 = tm*64+tg*2, t0+1)
// and 32 d. Each eps LDS read (the former bottleneck: ~10 cyc/ds_read_b128,
// 1 instr per energy) now serves 2 energies -> DS-pipe time halved; the
// cheap 3-level 8-lane shfl reduction is preserved (per-energy VALU equal).
// Blocks: 64 x sum_{tm=0}^{7}(2tm+2) = 64*72 = 4608 (was 8704).
// tanh(p+q) = 1 - 2/(1 + e^{2p} e^{2q}); grouped 4-per-rcp.
// ---------------------------------------------------------------------------
__global__ __launch_bounds__(256) void k_energy(const u16* __restrict__ EP,
                                                const u16* __restrict__ EQ,
                                                const float* __restrict__ v_attn,
                                                u16* __restrict__ Wx,
                                                float* __restrict__ l){
    __shared__ float eps[32][288];
    int tid = threadIdx.x;
    int blk = blockIdx.x;
    int b   = blk / 72;
    int pi  = blk % 72;
    int tm  = 0;
    while ((tm+1)*(tm+2) <= pi) ++tm;   // cum(tm) = tm^2+tm
    int pt  = pi - tm*(tm+1);           // 0 .. 2tm+1

    int tg  = tid >> 3;                 // 0..31: owns rows t0, t0+1
    int dg  = tid & 7;
    int d0  = dg * 32;
    int t0  = tm*64 + tg*2;

    // stage EP rows [pt*32, pt*32+32) as fp32 into padded layout
    #pragma unroll
    for (int i = 0; i < 8; ++i){
        int idx = tid + i*256;            // 0..2047, 4 bf16 each
        int row = idx >> 6;
        int c4  = (idx & 63) * 4;
        int pc  = c4 + ((c4 >> 5) << 2);  // +4 dwords per 32-chunk
        u16x4 v4 = *(const u16x4*)&EP[((size_t)((pt*32 + row)*B_ + b))*D_ + c4];
        float4 f4 = make_float4(bf2f(v4.x), bf2f(v4.y), bf2f(v4.z), bf2f(v4.w));
        *(float4*)&eps[row][pc] = f4;
    }

    float eq0[32], eq1[32], vm2[32], sv = 0.0f;
    #pragma unroll
    for (int i = 0; i < 8; ++i){
        u16x4 a4 = *(const u16x4*)&EQ[((size_t)(t0*B_ + b))*D_ + d0 + i*4];
        u16x4 b4 = *(const u16x4*)&EQ[((size_t)((t0+1)*B_ + b))*D_ + d0 + i*4];
        eq0[i*4+0] = bf2f(a4.x); eq0[i*4+1] = bf2f(a4.y);
        eq0[i*4+2] = bf2f(a4.z); eq0[i*4+3] = bf2f(a4.w);
        eq1[i*4+0] = bf2f(b4.x); eq1[i*4+1] = bf2f(b4.y);
        eq1[i*4+2] = bf2f(b4.z); eq1[i*4+3] = bf2f(b4.w);
    }
    #pragma unroll
    for (int i = 0; i < 32; ++i){
        float v = v_attn[d0 + i];
        sv += v;
        vm2[i] = -2.0f * v;
    }
    barrier_lgkm();

    float lsum0 = 0.0f, lsum1 = 0.0f;
    for (int tpl = 0; tpl < 32; ++tpl){
        int tp = pt*32 + tpl;
        float a0 = sv, a1 = sv;
        #pragma unroll
        for (int g = 0; g < 8; ++g){
            float4 ep = *(const float4*)&eps[tpl][dg*36 + 4*g];
            // row t0
            {
                float da = fmaf(ep.x, eq0[4*g+0], 1.0f);
                float db = fmaf(ep.y, eq0[4*g+1], 1.0f);
                float dc = fmaf(ep.z, eq0[4*g+2], 1.0f);
                float dd = fmaf(ep.w, eq0[4*g+3], 1.0f);
                float dab = da * db, dcd = dc * dd;
                float nab = fmaf(vm2[4*g+1], da, vm2[4*g+0] * db);
                float ncd = fmaf(vm2[4*g+3], dc, vm2[4*g+2] * dd);
                float num = fmaf(ncd, dab, nab * dcd);
                a0 = fmaf(num, __builtin_amdgcn_rcpf(dab * dcd), a0);
            }
            // row t0+1 (shares the ep read)
            {
                float da = fmaf(ep.x, eq1[4*g+0], 1.0f);
                float db = fmaf(ep.y, eq1[4*g+1], 1.0f);
                float dc = fmaf(ep.z, eq1[4*g+2], 1.0f);
                float dd = fmaf(ep.w, eq1[4*g+3], 1.0f);
                float dab = da * db, dcd = dc * dd;
                float nab = fmaf(vm2[4*g+1], da, vm2[4*g+0] * db);
                float ncd = fmaf(vm2[4*g+3], dc, vm2[4*g+2] * dd);
                float num = fmaf(ncd, dab, nab * dcd);
                a1 = fmaf(num, __builtin_amdgcn_rcpf(dab * dcd), a1);
            }
        }
        a0 += __shfl_xor(a0, 1); a0 += __shfl_xor(a0, 2); a0 += __shfl_xor(a0, 4);
        a1 += __shfl_xor(a1, 1); a1 += __shfl_xor(a1, 2); a1 += __shfl_xor(a1, 4);
        if (dg == 0){
            if (tp < t0){
                u16 peb = f2bf(__expf(a0));
                Wx[((size_t)(b*T_ + t0))*T_ + tp] = peb;
                lsum0 += bf2f(peb);
            }
            if (tp < t0 + 1){
                u16 peb = f2bf(__expf(a1));
                Wx[((size_t)(b*T_ + t0 + 1))*T_ + tp] = peb;
                lsum1 += bf2f(peb);
            }
        }
    }
    if (dg == 0){
        if (lsum0 != 0.0f) atomicAdd(&l[b*T_ + t0], lsum0);
        if (lsum1 != 0.0f) atomicAdd(&l[b*T_ + t0 + 1], lsum1);
    }
}

// ---------------------------------------------------------------------------
// K6: ctx[b][t][d] = (sum_t' Wx[b][t][t'] * h[t'][d]) / l[b][t]; t=0 -> h[0].
// TRIANGULAR K-loop (kk <= m0); stride-88 LDS.
// ---------------------------------------------------------------------------
__global__ __launch_bounds__(256) void k_ctx(const u16* __restrict__ Wx,
                                             u16* __restrict__ HC,
                                             const float* __restrict__ l){
    __shared__ u16 As[64][88];
    __shared__ u16 Ws[64][88];
    int tid  = threadIdx.x;
    int lane = tid & 63;
    int w    = tid >> 6;
    int col  = lane & 15;
    int quad = lane >> 4;
    int b    = blockIdx.y;
    int m0   = (blockIdx.x >> 2) * 64;   // t tile
    int n0   = (blockIdx.x & 3) * 64;    // d tile

    const u16* A = Wx + (size_t)b * T_ * T_;

    f32x4 acc[4];
    #pragma unroll
    for (int nt = 0; nt < 4; ++nt)
        #pragma unroll
        for (int r = 0; r < 4; ++r) acc[nt][r] = 0.0f;

    int kmax = m0 + 64;                  // strictly-past columns only
    for (int kk = 0; kk < kmax; kk += 64){
        #pragma unroll
        for (int i = 0; i < 2; ++i){
            int idx = tid + i*256;
            int r   = idx >> 3;
            int c8  = (idx & 7) * 8;
            *(s16x8*)&As[r][c8] = *(const s16x8*)&A[(size_t)(m0 + r)*T_ + kk + c8];
        }
        #pragma unroll
        for (int i = 0; i < 8; ++i){
            int idx = tid + i*256;
            int k   = idx >> 5;
            int n2  = (idx & 31) * 2;
            u16x2 v2 = *(const u16x2*)&HC[((size_t)((kk + k)*B_ + b))*D2_ + n0 + n2];
            Ws[n2][k]   = v2.x;
            Ws[n2+1][k] = v2.y;
        }
        barrier_lgkm();
        #pragma unroll
        for (int ks = 0; ks < 2; ++ks){
            s16x8 a = *(const s16x8*)&As[w*16 + col][ks*32 + quad*8];
            #pragma unroll
            for (int nt = 0; nt < 4; ++nt){
                s16x8 bb = *(const s16x8*)&Ws[nt*16 + col][ks*32 + quad*8];
                acc[nt] = __builtin_amdgcn_mfma_f32_16x16x32_bf16(a, bb, acc[nt], 0, 0, 0);
            }
        }
        barrier_lgkm();
    }

    float linv[4];
    #pragma unroll
    for (int r = 0; r < 4; ++r){
        int t = m0 + w*16 + quad*4 + r;
        float lv = (t > 0) ? l[b*T_ + t] : 1.0f;
        linv[r] = 1.0f / lv;
    }
    #pragma unroll
    for (int nt = 0; nt < 4; ++nt){
        int n = n0 + nt*16 + col;
        #pragma unroll
        for (int r = 0; r < 4; ++r){
            int t = m0 + w*16 + quad*4 + r;
            u16 ov;
            if (t == 0) ov = HC[(size_t)b*D2_ + n];          // ctx(0) = h(0)
            else        ov = f2bf(acc[nt][r] * linv[r]);
            HC[((size_t)(t*B_ + b))*D2_ + D_ + n] = ov;
        }
    }
}

// ---------------------------------------------------------------------------
extern "C" void kernel_launch(void* const* d_in, const int* in_sizes, int n_in,
                              void* d_out, int out_size, void* d_ws, size_t ws_size,
                              hipStream_t stream){
    const int*   x     = (const int*)d_in[0];
    const float* embed = (const float*)d_in[1];
    const float* W_ih  = (const float*)d_in[2];
    const float* W_hh  = (const float*)d_in[3];
    const float* b_h   = (const float*)d_in[4];
    const float* W_att = (const float*)d_in[5];
    const float* U_att = (const float*)d_in[6];
    const float* v_att = (const float*)d_in[7];
    const float* fc_W  = (const float*)d_in[8];
    const float* fc_b  = (const float*)d_in[9];

    char* ws = (char*)d_ws;
    float* EW   = (float*)ws;                       // 0.5 MB (dead after k_gather)
    u16*   fcWb = (u16*)ws;                         // 0.5 MB bf16 fc_W^T, ALIASES EW
    u16*   HC   = (u16*)(ws + 524288);              // 32 MB  [h|ctx] bf16
    u16*   EP   = (u16*)(ws + 34078720);            // 16 MB  exp(2*P) bf16
    u16*   EQ   = (u16*)(ws + 50855936);            // 16 MB  exp(2*Q) bf16 (EP+32768*256)
    float* XP   = (float*)(ws + 34078720);          // 32 MB  fp32, ALIASES EP+EQ (dead after k_rnn)
    float* l    = (float*)(ws + 67633152);          // 128 KB row sums
    u16*   Wab  = (u16*)(ws + 67764224);            // 128 KB bf16 W_att^T
    u16*   Uab  = (u16*)(ws + 67895296);            // 128 KB bf16 U_att^T (contig after Wab)
    u16*   Wx   = (u16*)d_out;                      // 33.5 MB scratch in d_out (dead until fc)

    (void)hipMemsetAsync(d_out, 0, (size_t)B_*T_*T_*2, stream);   // zero Wx (upper triangle stays 0)
    (void)hipMemsetAsync(l, 0, B_*T_*4, stream);

    // NOTE: fcWb aliases EW — k_cvt3 must run BEFORE k_ew? No: fcWb is only
    // READ by k_fc (last); EW is read by k_gather. Order: ew, gather use EW;
    // cvt3 then overwrites the region with fcWb. Keep cvt3 AFTER gather.
    k_ew    <<<dim3(V_),          dim3(256), 0, stream>>>(embed, W_ih, b_h, EW);
    k_gather<<<dim3(T_*B_/4),     dim3(256), 0, stream>>>(x, EW, XP);
    k_cvt3  <<<dim3(1536),        dim3(256), 0, stream>>>(W_att, U_att, fc_W, Wab, Uab, fcWb);
    k_rnn   <<<dim3(16),          dim3(512), 0, stream>>>(XP, W_hh, HC);
    // merged P/Q projection: one GEMM over [Wab|Uab], A staged once
    k_gemm  <<<dim3(512, 8),      dim3(256), 0, stream>>>(HC, D2_, Wab, nullptr, (void*)EP, D_, D2_, 3);
    k_energy<<<dim3(B_*72),       dim3(256), 0, stream>>>(EP, EQ, v_att, Wx, l);
    k_ctx   <<<dim3(32, B_),      dim3(256), 0, stream>>>(Wx, HC, l);
    k_fc    <<<dim3(256, 4),      dim3(512), 0, stream>>>(HC, fcWb, fc_b, (float*)d_out);
}

// Round 9
// 713.431 us; speedup vs baseline: 1.0079x; 1.0079x over previous
//
#include <hip/hip_runtime.h>
#include <hip/hip_bf16.h>

#define B_  64
#define T_  512
#define V_  512
#define E_  128
#define D_  256
#define D2_ 512

typedef unsigned short u16;
typedef unsigned int   u32;
typedef short s16x8 __attribute__((ext_vector_type(8)));
typedef _Float16 f16x8 __attribute__((ext_vector_type(8)));
typedef float f32x4 __attribute__((ext_vector_type(4)));
typedef unsigned short u16x2 __attribute__((ext_vector_type(2)));
typedef unsigned short u16x4 __attribute__((ext_vector_type(4)));

__device__ __forceinline__ float bf2f(u16 u){
    union { u32 i; float f; } c; c.i = ((u32)u) << 16; return c.f;
}
__device__ __forceinline__ u16 f2bf(float f){
    union { float f; u32 i; } c; c.f = f;
    u32 u = c.i;
    return (u16)((u + 0x7fffu + ((u >> 16) & 1u)) >> 16);
}
__device__ __forceinline__ u16 f2h(float f){
    union { _Float16 h; u16 u; } c; c.h = (_Float16)f; return c.u;
}
// tanh for bounded args (|x| <~ 20): 1 - 2/(e^{2x}+1).
__device__ __forceinline__ float tanh_b(float x){
    float e = __expf(2.0f * x);
    return fmaf(-2.0f, __builtin_amdgcn_rcpf(e + 1.0f), 1.0f);
}
// Workgroup barrier that only drains LDS (lgkm) — leaves global loads/stores
// in flight. Safe when cross-wave communication is LDS-only.
__device__ __forceinline__ void barrier_lgkm(){
    asm volatile("s_waitcnt lgkmcnt(0)\n\ts_barrier" ::: "memory");
}

// ---------------------------------------------------------------------------
// K1 (fused): blocks < 512: EW[v,d] = embed[v] @ W_ih + b_h  (fp32 exact).
// blocks >= 512: transpose+convert the three weight matrices to bf16:
//   Wab[n*256+k] = bf16(W_att[k*256+n]); Uab likewise; fcWb[n*512+k].
// ---------------------------------------------------------------------------
__global__ __launch_bounds__(256) void k_ew_cvt(const float* __restrict__ embed,
                                                const float* __restrict__ W_ih,
                                                const float* __restrict__ b_h,
                                                float* __restrict__ EW,
                                                const float* __restrict__ W_att,
                                                const float* __restrict__ U_att,
                                                const float* __restrict__ fc_W,
                                                u16* __restrict__ Wab,
                                                u16* __restrict__ Uab,
                                                u16* __restrict__ fcWb){
    __shared__ float er[E_];
    int blk = blockIdx.x;
    int tid = threadIdx.x;
    if (blk < V_){
        if (tid < E_) er[tid] = embed[blk*E_ + tid];
        __syncthreads();
        float acc = b_h[tid];
        #pragma unroll 4
        for (int e = 0; e < E_; ++e) acc += er[e] * W_ih[e*D_ + tid];
        EW[blk*D_ + tid] = acc;
    } else {
        int i = (blk - V_) * 256 + tid;
        if (i < 65536){
            int n = i >> 8, k = i & 255;
            Wab[i] = f2bf(W_att[k*D_ + n]);
        } else if (i < 131072){
            int j = i - 65536;
            int n = j >> 8, k = j & 255;
            Uab[j] = f2bf(U_att[k*D_ + n]);
        } else {
            int j = i - 131072;
            int n = j >> 9, k = j & 511;
            fcWb[j] = f2bf(fc_W[k*V_ + n]);
        }
    }
}

// ---------------------------------------------------------------------------
// K2: sequential h-chain. 16 blocks x 4 batches (M=4), 512 threads (8 waves,
// 2/SIMD). Single fp16 MFMA pass (proven round 5/7: 260 us).
// v7: XP buffer eliminated — the x-projection row is gathered DIRECTLY from
// EW (512 KB, L2-resident). Pipeline: vocab index vnext[r] for step t+1 is
// loaded 2 steps ahead; the EW row load for t+1 is issued during step t
// (one full step ~1100 cyc of latency cover, same in-flight-across-barrier
// structure as the XP prefetch it replaces).
// ---------------------------------------------------------------------------
__global__ __launch_bounds__(512, 2) void k_rnn(const int* __restrict__ x,
                                                const float* __restrict__ EW,
                                                const float* __restrict__ W_hh,
                                                u16* __restrict__ HC){
    __shared__ u16 hf[2][4][272];   // fp16 bits of h, double-buffered
    int tid  = threadIdx.x;
    int lane = tid & 63;
    int w    = tid >> 6;          // wave 0..7: n-range w*32..w*32+31
    int col  = lane & 15;
    int colA = col & 3;           // A-row alias (rows 4..15 duplicate 0..3)
    int quad = lane >> 4;
    int bb0  = blockIdx.x * 4;
    int dofs = w*32 + col;        // EW column base (+ nt*16)

    // Preload W_hh B-fragments (fp16): k = ks*32+quad*8+j, n = w*32+nt*16+col
    f16x8 bfh[2][8];
    #pragma unroll
    for (int nt = 0; nt < 2; ++nt){
        int n = w*32 + nt*16 + col;
        #pragma unroll
        for (int ks = 0; ks < 8; ++ks){
            f16x8 th;
            #pragma unroll
            for (int j = 0; j < 8; ++j){
                int k = ks*32 + quad*8 + j;
                th[j] = (_Float16)W_hh[k*D_ + n];
            }
            bfh[nt][ks] = th;
        }
    }
    for (int i = tid; i < 2*4*272; i += 512) (&hf[0][0][0])[i] = 0;

    u16* hc = HC + (size_t)bb0*D2_ + w*32 + col;      // + r*D2_ + nt*16

    int vnext[4];
    float ewv[2][4];
    {
        int vcur[4];
        #pragma unroll
        for (int r = 0; r < 4; ++r) vcur[r]  = x[(bb0 + r)*T_ + 0];
        #pragma unroll
        for (int r = 0; r < 4; ++r) vnext[r] = x[(bb0 + r)*T_ + 1];
        #pragma unroll
        for (int nt = 0; nt < 2; ++nt)
            #pragma unroll
            for (int r = 0; r < 4; ++r)
                ewv[nt][r] = EW[vcur[r]*D_ + dofs + nt*16];   // quads duplicate
    }
    __syncthreads();

    for (int t = 0; t < T_; ++t){
        int rb = t & 1, wb = rb ^ 1;
        f32x4 acc[2];
        #pragma unroll
        for (int nt = 0; nt < 2; ++nt)
            #pragma unroll
            for (int r = 0; r < 4; ++r) acc[nt][r] = ewv[nt][r];

        // bulk-load all A-fragments for this step (8 ds_read_b128, pipelined)
        f16x8 ah[8];
        #pragma unroll
        for (int ks = 0; ks < 8; ++ks)
            ah[ks] = *(const f16x8*)&hf[rb][colA][ks*32 + quad*8];

        // prefetch next step's x-projection row from EW (in flight across
        // the raw barrier); vocab index for t+2 prefetched alongside.
        if (t + 1 < T_){
            #pragma unroll
            for (int nt = 0; nt < 2; ++nt)
                #pragma unroll
                for (int r = 0; r < 4; ++r)
                    ewv[nt][r] = EW[vnext[r]*D_ + dofs + nt*16];
        }
        if (t + 2 < T_){
            #pragma unroll
            for (int r = 0; r < 4; ++r) vnext[r] = x[(bb0 + r)*T_ + t + 2];
        }

        #pragma unroll
        for (int ks = 0; ks < 8; ++ks){
            acc[0] = __builtin_amdgcn_mfma_f32_16x16x32_f16(ah[ks], bfh[0][ks], acc[0], 0, 0, 0);
            acc[1] = __builtin_amdgcn_mfma_f32_16x16x32_f16(ah[ks], bfh[1][ks], acc[1], 0, 0, 0);
        }

        // tail: lane owns (r = quad, nt = 0..1); static extracts via cndmask
        #pragma unroll
        for (int nt = 0; nt < 2; ++nt){
            f32x4 s = acc[nt];
            float v = (quad & 2) ? ((quad & 1) ? s[3] : s[2])
                                 : ((quad & 1) ? s[1] : s[0]);
            float h  = tanh_b(v);
            int n    = w*32 + nt*16 + col;
            hf[wb][quad][n]      = f2h(h);    // fp16 for the recurrence
            hc[quad*D2_ + nt*16] = f2bf(h);   // bf16 for downstream (unchanged)
        }
        hc += (size_t)B_*D2_;
        barrier_lgkm();   // h_t LDS visible; HC stores/EW loads stay in flight
    }
}

// ---------------------------------------------------------------------------
// Generic MFMA GEMM: out[M=32768, N] = A[M,K](bf16, lda) @ Wb[N,K](bf16).
// mode 3: out bf16 = exp(2*acc), N=512 over [Wab|Uab]: n<256 -> EP[m*256+n],
//         n>=256 -> EQ[m*256+n-256] (EQ = EP + 32768*256, contiguous).
// LDS stride 88 u16 = 44 dw (12 mod 32): balanced 8 lanes/bank-group.
// ---------------------------------------------------------------------------
__global__ __launch_bounds__(256) void k_gemm(const u16* __restrict__ A, int lda,
                                              const u16* __restrict__ Wb,
                                              const float* __restrict__ bias,
                                              void* __restrict__ out,
                                              int K, int N, int mode){
    __shared__ u16 As[64][88];
    __shared__ u16 Ws[64][88];
    int tid  = threadIdx.x;
    int lane = tid & 63;
    int w    = tid >> 6;
    int col  = lane & 15;
    int quad = lane >> 4;
    int m0   = blockIdx.x * 64;
    int n0   = blockIdx.y * 64;

    f32x4 acc[4];
    #pragma unroll
    for (int nt = 0; nt < 4; ++nt)
        #pragma unroll
        for (int r = 0; r < 4; ++r) acc[nt][r] = 0.0f;

    for (int kk = 0; kk < K; kk += 64){
        #pragma unroll
        for (int i = 0; i < 2; ++i){
            int idx = tid + i*256;        // 0..511
            int r   = idx >> 3;           // row 0..63
            int c8  = (idx & 7) * 8;      // k-oct
            *(s16x8*)&As[r][c8] = *(const s16x8*)&A [(size_t)(m0 + r)*lda + kk + c8];
            *(s16x8*)&Ws[r][c8] = *(const s16x8*)&Wb[(size_t)(n0 + r)*K   + kk + c8];
        }
        barrier_lgkm();
        #pragma unroll
        for (int ks = 0; ks < 2; ++ks){
            s16x8 a = *(const s16x8*)&As[w*16 + col][ks*32 + quad*8];
            #pragma unroll
            for (int nt = 0; nt < 4; ++nt){
                s16x8 b = *(const s16x8*)&Ws[nt*16 + col][ks*32 + quad*8];
                acc[nt] = __builtin_amdgcn_mfma_f32_16x16x32_bf16(a, b, acc[nt], 0, 0, 0);
            }
        }
        barrier_lgkm();
    }
    #pragma unroll
    for (int nt = 0; nt < 4; ++nt){
        int n = n0 + nt*16 + col;
        float bv = (mode == 1 && bias) ? bias[n] : 0.0f;
        #pragma unroll
        for (int r = 0; r < 4; ++r){
            int m = m0 + w*16 + quad*4 + r;
            float v = acc[nt][r] + bv;
            if (mode == 1){
                int b = m & 63, t = m >> 6;
                ((float*)out)[(size_t)(b*T_ + t)*V_ + n] = v;
            } else if (mode == 2){
                ((u16*)out)[(size_t)m*N + n] = f2bf(__expf(2.0f * v));
            } else if (mode == 3){
                u16* dst = (u16*)out + ((size_t)(n >> 8)) * ((size_t)32768 * 256);
                dst[(size_t)m*256 + (n & 255)] = f2bf(__expf(2.0f * v));
            } else {
                ((u16*)out)[(size_t)m*N + n] = f2bf(v);
            }
        }
    }
}

// ---------------------------------------------------------------------------
// K4b: final fc layer, 128x128x64 tile (512 thr, 8 waves as 2Mx4N).
// ---------------------------------------------------------------------------
__global__ __launch_bounds__(512) void k_fc(const u16* __restrict__ A,
                                            const u16* __restrict__ Wb,
                                            const float* __restrict__ bias,
                                            float* __restrict__ out){
    __shared__ u16 As[128][88];
    __shared__ u16 Ws[128][88];
    int tid  = threadIdx.x;
    int lane = tid & 63;
    int w    = tid >> 6;        // 8 waves
    int wm   = w >> 2;          // 0..1: M-half
    int wn   = w & 3;           // 0..3: N-quarter
    int col  = lane & 15;
    int quad = lane >> 4;
    int m0   = blockIdx.x * 128;
    int n0   = blockIdx.y * 128;

    f32x4 acc[4][2];
    #pragma unroll
    for (int mt = 0; mt < 4; ++mt)
        #pragma unroll
        for (int nt = 0; nt < 2; ++nt)
            #pragma unroll
            for (int r = 0; r < 4; ++r) acc[mt][nt][r] = 0.0f;

    for (int kk = 0; kk < D2_; kk += 64){
        #pragma unroll
        for (int i = 0; i < 2; ++i){
            int idx = tid + i*512;        // 0..1023
            int r   = idx >> 3;           // row 0..127
            int c8  = (idx & 7) * 8;
            *(s16x8*)&As[r][c8] = *(const s16x8*)&A [(size_t)(m0 + r)*D2_ + kk + c8];
            *(s16x8*)&Ws[r][c8] = *(const s16x8*)&Wb[(size_t)(n0 + r)*D2_ + kk + c8];
        }
        barrier_lgkm();
        #pragma unroll
        for (int ks = 0; ks < 2; ++ks){
            s16x8 b0 = *(const s16x8*)&Ws[wn*32 +      col][ks*32 + quad*8];
            s16x8 b1 = *(const s16x8*)&Ws[wn*32 + 16 + col][ks*32 + quad*8];
            #pragma unroll
            for (int mt = 0; mt < 4; ++mt){
                s16x8 a = *(const s16x8*)&As[wm*64 + mt*16 + col][ks*32 + quad*8];
                acc[mt][0] = __builtin_amdgcn_mfma_f32_16x16x32_bf16(a, b0, acc[mt][0], 0, 0, 0);
                acc[mt][1] = __builtin_amdgcn_mfma_f32_16x16x32_bf16(a, b1, acc[mt][1], 0, 0, 0);
            }
        }
        barrier_lgkm();
    }
    #pragma unroll
    for (int nt = 0; nt < 2; ++nt){
        int n = n0 + wn*32 + nt*16 + col;
        float bv = bias[n];
        #pragma unroll
        for (int mt = 0; mt < 4; ++mt){
            #pragma unroll
            for (int r = 0; r < 4; ++r){
                int m = m0 + wm*64 + mt*16 + quad*4 + r;
                int b = m & 63, t = m >> 6;
                out[(size_t)(b*T_ + t)*V_ + n] = acc[mt][nt][r] + bv;
            }
        }
    }
}

// ---------------------------------------------------------------------------
// K5: energies (round-7 proven form). Block = (b, tt, pt), pt <= tt, 32x32
// (t,t') tile over d=256. tanh(p+q) = 1 - 2/(1 + e^{2p} e^{2q}); 4-per-rcp.
// Writes only tp < t entries of Wx; no l accumulation (k_ctx derives row
// sums from the staged Wx values directly).
// ---------------------------------------------------------------------------
__global__ __launch_bounds__(256) void k_energy(const u16* __restrict__ EP,
                                                const u16* __restrict__ EQ,
                                                const float* __restrict__ v_attn,
                                                u16* __restrict__ Wx){
    __shared__ float eps[32][288];
    int tid = threadIdx.x;
    int blk = blockIdx.x;
    int b   = blk / 136;
    int pi  = blk % 136;
    int tt  = 0;
    while ((tt+1)*(tt+2)/2 <= pi) ++tt;
    int pt  = pi - tt*(tt+1)/2;

    int t_l = tid >> 3;
    int dg  = tid & 7;
    int d0  = dg * 32;
    int t   = tt*32 + t_l;

    // stage EP rows [pt*32, pt*32+32) as fp32 into padded layout
    #pragma unroll
    for (int i = 0; i < 8; ++i){
        int idx = tid + i*256;            // 0..2047, 4 bf16 each
        int row = idx >> 6;
        int c4  = (idx & 63) * 4;
        int pc  = c4 + ((c4 >> 5) << 2);  // +4 dwords per 32-chunk
        u16x4 v4 = *(const u16x4*)&EP[((size_t)((pt*32 + row)*B_ + b))*D_ + c4];
        float4 f4 = make_float4(bf2f(v4.x), bf2f(v4.y), bf2f(v4.z), bf2f(v4.w));
        *(float4*)&eps[row][pc] = f4;
    }

    float eq[32], vm2[32], sv = 0.0f;
    #pragma unroll
    for (int i = 0; i < 8; ++i){
        u16x4 v4 = *(const u16x4*)&EQ[((size_t)(t*B_ + b))*D_ + d0 + i*4];
        eq[i*4+0] = bf2f(v4.x); eq[i*4+1] = bf2f(v4.y);
        eq[i*4+2] = bf2f(v4.z); eq[i*4+3] = bf2f(v4.w);
    }
    #pragma unroll
    for (int i = 0; i < 32; ++i){
        float v = v_attn[d0 + i];
        sv += v;
        vm2[i] = -2.0f * v;
    }
    barrier_lgkm();

    for (int tpl = 0; tpl < 32; ++tpl){
        int tp = pt*32 + tpl;
        float acc = sv;
        #pragma unroll
        for (int g = 0; g < 8; ++g){
            float4 ep = *(const float4*)&eps[tpl][dg*36 + 4*g];
            float da = fmaf(ep.x, eq[4*g+0], 1.0f);
            float db = fmaf(ep.y, eq[4*g+1], 1.0f);
            float dc = fmaf(ep.z, eq[4*g+2], 1.0f);
            float dd = fmaf(ep.w, eq[4*g+3], 1.0f);
            float dab = da * db;
            float dcd = dc * dd;
            float nab = fmaf(vm2[4*g+1], da, vm2[4*g+0] * db);
            float ncd = fmaf(vm2[4*g+3], dc, vm2[4*g+2] * dd);
            float num = fmaf(ncd, dab, nab * dcd);
            acc = fmaf(num, __builtin_amdgcn_rcpf(dab * dcd), acc);
        }
        acc += __shfl_xor(acc, 1);
        acc += __shfl_xor(acc, 2);
        acc += __shfl_xor(acc, 4);
        if (dg == 0 && tp < t){
            Wx[((size_t)(b*T_ + t))*T_ + tp] = f2bf(__expf(acc));
        }
    }
}

// ---------------------------------------------------------------------------
// K6: ctx[b][t][d] = (sum_t' Wx[b][t][t'] * h[t'][d]) / l[b][t]; t=0 -> h[0].
// TRIANGULAR K-loop (kk <= m0). v2: no memset / no l buffer needed —
//  (a) the diagonal tile (kk == m0) is MASKED during As staging (entries with
//      tp >= t forced to 0), so Wx garbage above the diagonal never enters;
//  (b) row sums l[t] = sum_tp Wx[t][tp] are accumulated per-thread from the
//      staged (post-mask) values, 8-lane shfl-reduced, and stored in LDS —
//      identical bf16 values as before, fp32-summed in a different order.
// ---------------------------------------------------------------------------
__global__ __launch_bounds__(256) void k_ctx(const u16* __restrict__ Wx,
                                             u16* __restrict__ HC){
    __shared__ u16 As[64][88];
    __shared__ u16 Ws[64][88];
    __shared__ float rs[64];
    int tid  = threadIdx.x;
    int lane = tid & 63;
    int w    = tid >> 6;
    int col  = lane & 15;
    int quad = lane >> 4;
    int b    = blockIdx.y;
    int m0   = (blockIdx.x >> 2) * 64;   // t tile
    int n0   = (blockIdx.x & 3) * 64;    // d tile

    const u16* A = Wx + (size_t)b * T_ * T_;

    int r0 = tid >> 3;                   // As row for i=0 (i=1: r0+32)
    int c8 = (tid & 7) * 8;
    float rsum0 = 0.0f, rsum1 = 0.0f;

    f32x4 acc[4];
    #pragma unroll
    for (int nt = 0; nt < 4; ++nt)
        #pragma unroll
        for (int r = 0; r < 4; ++r) acc[nt][r] = 0.0f;

    int kmax = m0 + 64;                  // strictly-past columns only
    for (int kk = 0; kk < kmax; kk += 64){
        bool diag = (kk == m0);
        #pragma unroll
        for (int i = 0; i < 2; ++i){
            int r = r0 + i*32;
            s16x8 v = *(const s16x8*)&A[(size_t)(m0 + r)*T_ + kk + c8];
            if (diag){
                #pragma unroll
                for (int j = 0; j < 8; ++j)
                    if (c8 + j >= r) v[j] = 0;   // tp >= t -> zero
            }
            *(s16x8*)&As[r][c8] = v;
            float s = 0.0f;
            #pragma unroll
            for (int j = 0; j < 8; ++j) s += bf2f((u16)v[j]);
            if (i == 0) rsum0 += s; else rsum1 += s;
        }
        #pragma unroll
        for (int i = 0; i < 8; ++i){
            int idx = tid + i*256;
            int k   = idx >> 5;
            int n2  = (idx & 31) * 2;
            u16x2 v2 = *(const u16x2*)&HC[((size_t)((kk + k)*B_ + b))*D2_ + n0 + n2];
            Ws[n2][k]   = v2.x;
            Ws[n2+1][k] = v2.y;
        }
        barrier_lgkm();
        #pragma unroll
        for (int ks = 0; ks < 2; ++ks){
            s16x8 a = *(const s16x8*)&As[w*16 + col][ks*32 + quad*8];
            #pragma unroll
            for (int nt = 0; nt < 4; ++nt){
                s16x8 bb = *(const s16x8*)&Ws[nt*16 + col][ks*32 + quad*8];
                acc[nt] = __builtin_amdgcn_mfma_f32_16x16x32_bf16(a, bb, acc[nt], 0, 0, 0);
            }
        }
        barrier_lgkm();
    }

    // row sums: reduce across the 8 threads sharing each As row
    rsum0 += __shfl_xor(rsum0, 1); rsum0 += __shfl_xor(rsum0, 2); rsum0 += __shfl_xor(rsum0, 4);
    rsum1 += __shfl_xor(rsum1, 1); rsum1 += __shfl_xor(rsum1, 2); rsum1 += __shfl_xor(rsum1, 4);
    if ((tid & 7) == 0){ rs[r0] = rsum0; rs[r0 + 32] = rsum1; }
    barrier_lgkm();

    float linv[4];
    #pragma unroll
    for (int r = 0; r < 4; ++r){
        int rr = w*16 + quad*4 + r;          // t - m0
        float lv = (m0 + rr > 0) ? rs[rr] : 1.0f;
        linv[r] = 1.0f / lv;
    }
    #pragma unroll
    for (int nt = 0; nt < 4; ++nt){
        int n = n0 + nt*16 + col;
        #pragma unroll
        for (int r = 0; r < 4; ++r){
            int t = m0 + w*16 + quad*4 + r;
            u16 ov;
            if (t == 0) ov = HC[(size_t)b*D2_ + n];          // ctx(0) = h(0)
            else        ov = f2bf(acc[nt][r] * linv[r]);
            HC[((size_t)(t*B_ + b))*D2_ + D_ + n] = ov;
        }
    }
}

// ---------------------------------------------------------------------------
extern "C" void kernel_launch(void* const* d_in, const int* in_sizes, int n_in,
                              void* d_out, int out_size, void* d_ws, size_t ws_size,
                              hipStream_t stream){
    const int*   x     = (const int*)d_in[0];
    const float* embed = (const float*)d_in[1];
    const float* W_ih  = (const float*)d_in[2];
    const float* W_hh  = (const float*)d_in[3];
    const float* b_h   = (const float*)d_in[4];
    const float* W_att = (const float*)d_in[5];
    const float* U_att = (const float*)d_in[6];
    const float* v_att = (const float*)d_in[7];
    const float* fc_W  = (const float*)d_in[8];
    const float* fc_b  = (const float*)d_in[9];

    char* ws = (char*)d_ws;
    float* EW   = (float*)ws;                       // 512 KB (live through k_rnn)
    u16*   Wab  = (u16*)(ws + 524288);              // 128 KB bf16 W_att^T
    u16*   Uab  = (u16*)(ws + 655360);              // 128 KB bf16 U_att^T (contig)
    u16*   fcWb = (u16*)(ws + 786432);              // 512 KB bf16 fc_W^T
    u16*   HC   = (u16*)(ws + 1310720);             // 32 MB  [h|ctx] bf16
    u16*   EP   = (u16*)(ws + 34865152);            // 16 MB  exp(2*P) bf16
    u16*   EQ   = (u16*)(ws + 51642368);            // 16 MB  exp(2*Q) bf16 (EP+32768*256)
    u16*   Wx   = (u16*)d_out;                      // 33.5 MB scratch in d_out (dead until fc)

    k_ew_cvt<<<dim3(2048),        dim3(256), 0, stream>>>(embed, W_ih, b_h, EW,
                                                          W_att, U_att, fc_W,
                                                          Wab, Uab, fcWb);
    k_rnn   <<<dim3(16),          dim3(512), 0, stream>>>(x, EW, W_hh, HC);
    // merged P/Q projection: one GEMM over [Wab|Uab], A staged once
    k_gemm  <<<dim3(512, 8),      dim3(256), 0, stream>>>(HC, D2_, Wab, nullptr, (void*)EP, D_, D2_, 3);
    k_energy<<<dim3(B_*136),      dim3(256), 0, stream>>>(EP, EQ, v_att, Wx);
    k_ctx   <<<dim3(32, B_),      dim3(256), 0, stream>>>(Wx, HC);
    k_fc    <<<dim3(256, 4),      dim3(512), 0, stream>>>(HC, fcWb, fc_b, (float*)d_out);
}

// Round 10
// 686.032 us; speedup vs baseline: 1.0482x; 1.0399x over previous
//
#include <hip/hip_runtime.h>
#include <hip/hip_bf16.h>

#define B_  64
#define T_  512
#define V_  512
#define E_  128
#define D_  256
#define D2_ 512

typedef unsigned short u16;
typedef unsigned int   u32;
typedef short s16x8 __attribute__((ext_vector_type(8)));
typedef _Float16 f16x8 __attribute__((ext_vector_type(8)));
typedef float f32x4 __attribute__((ext_vector_type(4)));
typedef unsigned short u16x2 __attribute__((ext_vector_type(2)));
typedef unsigned short u16x4 __attribute__((ext_vector_type(4)));

__device__ __forceinline__ float bf2f(u16 u){
    union { u32 i; float f; } c; c.i = ((u32)u) << 16; return c.f;
}
__device__ __forceinline__ u16 f2bf(float f){
    union { float f; u32 i; } c; c.f = f;
    u32 u = c.i;
    return (u16)((u + 0x7fffu + ((u >> 16) & 1u)) >> 16);
}
__device__ __forceinline__ u16 f2h(float f){
    union { _Float16 h; u16 u; } c; c.h = (_Float16)f; return c.u;
}
// tanh for bounded args (|x| <~ 20): 1 - 2/(e^{2x}+1).
__device__ __forceinline__ float tanh_b(float x){
    float e = __expf(2.0f * x);
    return fmaf(-2.0f, __builtin_amdgcn_rcpf(e + 1.0f), 1.0f);
}
// Workgroup barrier that only drains LDS (lgkm) — leaves global loads/stores
// in flight. Safe when cross-wave communication is LDS-only.
__device__ __forceinline__ void barrier_lgkm(){
    asm volatile("s_waitcnt lgkmcnt(0)\n\ts_barrier" ::: "memory");
}

// ---------------------------------------------------------------------------
// K1 (fused): blocks < 512: EW[v,d] = embed[v] @ W_ih + b_h  (fp32 exact).
// blocks >= 512: transpose+convert the three weight matrices to bf16:
//   Wab[n*256+k] = bf16(W_att[k*256+n]); Uab likewise; fcWb[n*512+k].
// ---------------------------------------------------------------------------
__global__ __launch_bounds__(256) void k_ew_cvt(const float* __restrict__ embed,
                                                const float* __restrict__ W_ih,
                                                const float* __restrict__ b_h,
                                                float* __restrict__ EW,
                                                const float* __restrict__ W_att,
                                                const float* __restrict__ U_att,
                                                const float* __restrict__ fc_W,
                                                u16* __restrict__ Wab,
                                                u16* __restrict__ Uab,
                                                u16* __restrict__ fcWb){
    __shared__ float er[E_];
    int blk = blockIdx.x;
    int tid = threadIdx.x;
    if (blk < V_){
        if (tid < E_) er[tid] = embed[blk*E_ + tid];
        __syncthreads();
        float acc = b_h[tid];
        #pragma unroll 4
        for (int e = 0; e < E_; ++e) acc += er[e] * W_ih[e*D_ + tid];
        EW[blk*D_ + tid] = acc;
    } else {
        int i = (blk - V_) * 256 + tid;
        if (i < 65536){
            int n = i >> 8, k = i & 255;
            Wab[i] = f2bf(W_att[k*D_ + n]);
        } else if (i < 131072){
            int j = i - 65536;
            int n = j >> 8, k = j & 255;
            Uab[j] = f2bf(U_att[k*D_ + n]);
        } else {
            int j = i - 131072;
            int n = j >> 9, k = j & 511;
            fcWb[j] = f2bf(fc_W[k*V_ + n]);
        }
    }
}

// ---------------------------------------------------------------------------
// K1b: XP[t*64+b][d] = EW[x[b][t]][d]  (fp32, 32 MB; aliases EP/EQ region).
// Restored (round-9 lesson): the streaming XP layout lets k_rnn prefetch via
// a stepped pointer + constant offsets (zero per-step address VALU, L2-
// prefetch-friendly). In-loop EW gather cost +150 cyc/step in the serial
// chain — worth 64 MB of 6 TB/s streaming traffic in this 12 us kernel.
// ---------------------------------------------------------------------------
__global__ __launch_bounds__(256) void k_gather(const int* __restrict__ x,
                                                const float* __restrict__ EW,
                                                float* __restrict__ XP){
    int m = blockIdx.x * 4 + (threadIdx.x >> 6);   // row index t*64+b
    int lane = threadIdx.x & 63;
    int b = m & 63, t = m >> 6;
    int v = x[b*T_ + t];
    float4 val = *(const float4*)&EW[v*D_ + lane*4];
    *(float4*)&XP[(size_t)m*D_ + lane*4] = val;
}

// ---------------------------------------------------------------------------
// K2: sequential h-chain. 16 blocks x 4 batches (M=4), 512 threads (8 waves,
// 2/SIMD). Single fp16 MFMA pass. Proven round 5/7/8 form: 260 us.
// ---------------------------------------------------------------------------
__global__ __launch_bounds__(512, 2) void k_rnn(const float* __restrict__ XP,
                                                const float* __restrict__ W_hh,
                                                u16* __restrict__ HC){
    __shared__ u16 hf[2][4][272];   // fp16 bits of h, double-buffered
    int tid  = threadIdx.x;
    int lane = tid & 63;
    int w    = tid >> 6;          // wave 0..7: n-range w*32..w*32+31
    int col  = lane & 15;
    int colA = col & 3;           // A-row alias (rows 4..15 duplicate 0..3)
    int quad = lane >> 4;
    int bb0  = blockIdx.x * 4;

    // Preload W_hh B-fragments (fp16): k = ks*32+quad*8+j, n = w*32+nt*16+col
    f16x8 bfh[2][8];
    #pragma unroll
    for (int nt = 0; nt < 2; ++nt){
        int n = w*32 + nt*16 + col;
        #pragma unroll
        for (int ks = 0; ks < 8; ++ks){
            f16x8 th;
            #pragma unroll
            for (int j = 0; j < 8; ++j){
                int k = ks*32 + quad*8 + j;
                th[j] = (_Float16)W_hh[k*D_ + n];
            }
            bfh[nt][ks] = th;
        }
    }
    for (int i = tid; i < 2*4*272; i += 512) (&hf[0][0][0])[i] = 0;

    // stepped base pointers (advance by one t-slab per step)
    const float* p  = XP + (size_t)bb0*D_ + w*32 + col;       // + r*D_ + nt*16
    u16*         hc = HC + (size_t)bb0*D2_ + w*32 + col;      // + r*D2_ + nt*16

    float ewv[2][4];
    #pragma unroll
    for (int nt = 0; nt < 2; ++nt)
        #pragma unroll
        for (int r = 0; r < 4; ++r)
            ewv[nt][r] = p[r*D_ + nt*16];   // all lanes (quads duplicate)
    p += (size_t)B_*D_;
    __syncthreads();

    for (int t = 0; t < T_; ++t){
        int rb = t & 1, wb = rb ^ 1;
        f32x4 acc[2];
        #pragma unroll
        for (int nt = 0; nt < 2; ++nt)
            #pragma unroll
            for (int r = 0; r < 4; ++r) acc[nt][r] = ewv[nt][r];

        // bulk-load all A-fragments for this step (8 ds_read_b128, pipelined)
        f16x8 ah[8];
        #pragma unroll
        for (int ks = 0; ks < 8; ++ks)
            ah[ks] = *(const f16x8*)&hf[rb][colA][ks*32 + quad*8];

        // prefetch next step's xp (stays in flight across raw barrier)
        if (t + 1 < T_){
            #pragma unroll
            for (int nt = 0; nt < 2; ++nt)
                #pragma unroll
                for (int r = 0; r < 4; ++r)
                    ewv[nt][r] = p[r*D_ + nt*16];
        }
        p += (size_t)B_*D_;

        #pragma unroll
        for (int ks = 0; ks < 8; ++ks){
            acc[0] = __builtin_amdgcn_mfma_f32_16x16x32_f16(ah[ks], bfh[0][ks], acc[0], 0, 0, 0);
            acc[1] = __builtin_amdgcn_mfma_f32_16x16x32_f16(ah[ks], bfh[1][ks], acc[1], 0, 0, 0);
        }

        // tail: lane owns (r = quad, nt = 0..1); static extracts via cndmask
        #pragma unroll
        for (int nt = 0; nt < 2; ++nt){
            f32x4 s = acc[nt];
            float v = (quad & 2) ? ((quad & 1) ? s[3] : s[2])
                                 : ((quad & 1) ? s[1] : s[0]);
            float h  = tanh_b(v);
            int n    = w*32 + nt*16 + col;
            hf[wb][quad][n]      = f2h(h);    // fp16 for the recurrence
            hc[quad*D2_ + nt*16] = f2bf(h);   // bf16 for downstream (unchanged)
        }
        hc += (size_t)B_*D2_;
        barrier_lgkm();   // h_t LDS visible; HC stores/XP loads stay in flight
    }
}

// ---------------------------------------------------------------------------
// Generic MFMA GEMM: out[M=32768, N] = A[M,K](bf16, lda) @ Wb[N,K](bf16).
// mode 3: out bf16 = exp(2*acc), N=512 over [Wab|Uab]: n<256 -> EP[m*256+n],
//         n>=256 -> EQ[m*256+n-256] (EQ = EP + 32768*256, contiguous).
// LDS stride 88 u16 = 44 dw (12 mod 32): balanced 8 lanes/bank-group.
// ---------------------------------------------------------------------------
__global__ __launch_bounds__(256) void k_gemm(const u16* __restrict__ A, int lda,
                                              const u16* __restrict__ Wb,
                                              const float* __restrict__ bias,
                                              void* __restrict__ out,
                                              int K, int N, int mode){
    __shared__ u16 As[64][88];
    __shared__ u16 Ws[64][88];
    int tid  = threadIdx.x;
    int lane = tid & 63;
    int w    = tid >> 6;
    int col  = lane & 15;
    int quad = lane >> 4;
    int m0   = blockIdx.x * 64;
    int n0   = blockIdx.y * 64;

    f32x4 acc[4];
    #pragma unroll
    for (int nt = 0; nt < 4; ++nt)
        #pragma unroll
        for (int r = 0; r < 4; ++r) acc[nt][r] = 0.0f;

    for (int kk = 0; kk < K; kk += 64){
        #pragma unroll
        for (int i = 0; i < 2; ++i){
            int idx = tid + i*256;        // 0..511
            int r   = idx >> 3;           // row 0..63
            int c8  = (idx & 7) * 8;      // k-oct
            *(s16x8*)&As[r][c8] = *(const s16x8*)&A [(size_t)(m0 + r)*lda + kk + c8];
            *(s16x8*)&Ws[r][c8] = *(const s16x8*)&Wb[(size_t)(n0 + r)*K   + kk + c8];
        }
        barrier_lgkm();
        #pragma unroll
        for (int ks = 0; ks < 2; ++ks){
            s16x8 a = *(const s16x8*)&As[w*16 + col][ks*32 + quad*8];
            #pragma unroll
            for (int nt = 0; nt < 4; ++nt){
                s16x8 b = *(const s16x8*)&Ws[nt*16 + col][ks*32 + quad*8];
                acc[nt] = __builtin_amdgcn_mfma_f32_16x16x32_bf16(a, b, acc[nt], 0, 0, 0);
            }
        }
        barrier_lgkm();
    }
    #pragma unroll
    for (int nt = 0; nt < 4; ++nt){
        int n = n0 + nt*16 + col;
        float bv = (mode == 1 && bias) ? bias[n] : 0.0f;
        #pragma unroll
        for (int r = 0; r < 4; ++r){
            int m = m0 + w*16 + quad*4 + r;
            float v = acc[nt][r] + bv;
            if (mode == 1){
                int b = m & 63, t = m >> 6;
                ((float*)out)[(size_t)(b*T_ + t)*V_ + n] = v;
            } else if (mode == 2){
                ((u16*)out)[(size_t)m*N + n] = f2bf(__expf(2.0f * v));
            } else if (mode == 3){
                u16* dst = (u16*)out + ((size_t)(n >> 8)) * ((size_t)32768 * 256);
                dst[(size_t)m*256 + (n & 255)] = f2bf(__expf(2.0f * v));
            } else {
                ((u16*)out)[(size_t)m*N + n] = f2bf(v);
            }
        }
    }
}

// ---------------------------------------------------------------------------
// K4b: final fc layer, 128x128x64 tile (512 thr, 8 waves as 2Mx4N).
// ---------------------------------------------------------------------------
__global__ __launch_bounds__(512) void k_fc(const u16* __restrict__ A,
                                            const u16* __restrict__ Wb,
                                            const float* __restrict__ bias,
                                            float* __restrict__ out){
    __shared__ u16 As[128][88];
    __shared__ u16 Ws[128][88];
    int tid  = threadIdx.x;
    int lane = tid & 63;
    int w    = tid >> 6;        // 8 waves
    int wm   = w >> 2;          // 0..1: M-half
    int wn   = w & 3;           // 0..3: N-quarter
    int col  = lane & 15;
    int quad = lane >> 4;
    int m0   = blockIdx.x * 128;
    int n0   = blockIdx.y * 128;

    f32x4 acc[4][2];
    #pragma unroll
    for (int mt = 0; mt < 4; ++mt)
        #pragma unroll
        for (int nt = 0; nt < 2; ++nt)
            #pragma unroll
            for (int r = 0; r < 4; ++r) acc[mt][nt][r] = 0.0f;

    for (int kk = 0; kk < D2_; kk += 64){
        #pragma unroll
        for (int i = 0; i < 2; ++i){
            int idx = tid + i*512;        // 0..1023
            int r   = idx >> 3;           // row 0..127
            int c8  = (idx & 7) * 8;
            *(s16x8*)&As[r][c8] = *(const s16x8*)&A [(size_t)(m0 + r)*D2_ + kk + c8];
            *(s16x8*)&Ws[r][c8] = *(const s16x8*)&Wb[(size_t)(n0 + r)*D2_ + kk + c8];
        }
        barrier_lgkm();
        #pragma unroll
        for (int ks = 0; ks < 2; ++ks){
            s16x8 b0 = *(const s16x8*)&Ws[wn*32 +      col][ks*32 + quad*8];
            s16x8 b1 = *(const s16x8*)&Ws[wn*32 + 16 + col][ks*32 + quad*8];
            #pragma unroll
            for (int mt = 0; mt < 4; ++mt){
                s16x8 a = *(const s16x8*)&As[wm*64 + mt*16 + col][ks*32 + quad*8];
                acc[mt][0] = __builtin_amdgcn_mfma_f32_16x16x32_bf16(a, b0, acc[mt][0], 0, 0, 0);
                acc[mt][1] = __builtin_amdgcn_mfma_f32_16x16x32_bf16(a, b1, acc[mt][1], 0, 0, 0);
            }
        }
        barrier_lgkm();
    }
    #pragma unroll
    for (int nt = 0; nt < 2; ++nt){
        int n = n0 + wn*32 + nt*16 + col;
        float bv = bias[n];
        #pragma unroll
        for (int mt = 0; mt < 4; ++mt){
            #pragma unroll
            for (int r = 0; r < 4; ++r){
                int m = m0 + wm*64 + mt*16 + quad*4 + r;
                int b = m & 63, t = m >> 6;
                out[(size_t)(b*T_ + t)*V_ + n] = acc[mt][nt][r] + bv;
            }
        }
    }
}

// ---------------------------------------------------------------------------
// K5: energies (round-7 proven form). Block = (b, tt, pt), pt <= tt, 32x32
// (t,t') tile over d=256. tanh(p+q) = 1 - 2/(1 + e^{2p} e^{2q}); 4-per-rcp.
// Writes only tp < t entries of Wx; no l accumulation (k_ctx derives row
// sums from the staged Wx values directly).
// ---------------------------------------------------------------------------
__global__ __launch_bounds__(256) void k_energy(const u16* __restrict__ EP,
                                                const u16* __restrict__ EQ,
                                                const float* __restrict__ v_attn,
                                                u16* __restrict__ Wx){
    __shared__ float eps[32][288];
    int tid = threadIdx.x;
    int blk = blockIdx.x;
    int b   = blk / 136;
    int pi  = blk % 136;
    int tt  = 0;
    while ((tt+1)*(tt+2)/2 <= pi) ++tt;
    int pt  = pi - tt*(tt+1)/2;

    int t_l = tid >> 3;
    int dg  = tid & 7;
    int d0  = dg * 32;
    int t   = tt*32 + t_l;

    // stage EP rows [pt*32, pt*32+32) as fp32 into padded layout
    #pragma unroll
    for (int i = 0; i < 8; ++i){
        int idx = tid + i*256;            // 0..2047, 4 bf16 each
        int row = idx >> 6;
        int c4  = (idx & 63) * 4;
        int pc  = c4 + ((c4 >> 5) << 2);  // +4 dwords per 32-chunk
        u16x4 v4 = *(const u16x4*)&EP[((size_t)((pt*32 + row)*B_ + b))*D_ + c4];
        float4 f4 = make_float4(bf2f(v4.x), bf2f(v4.y), bf2f(v4.z), bf2f(v4.w));
        *(float4*)&eps[row][pc] = f4;
    }

    float eq[32], vm2[32], sv = 0.0f;
    #pragma unroll
    for (int i = 0; i < 8; ++i){
        u16x4 v4 = *(const u16x4*)&EQ[((size_t)(t*B_ + b))*D_ + d0 + i*4];
        eq[i*4+0] = bf2f(v4.x); eq[i*4+1] = bf2f(v4.y);
        eq[i*4+2] = bf2f(v4.z); eq[i*4+3] = bf2f(v4.w);
    }
    #pragma unroll
    for (int i = 0; i < 32; ++i){
        float v = v_attn[d0 + i];
        sv += v;
        vm2[i] = -2.0f * v;
    }
    barrier_lgkm();

    for (int tpl = 0; tpl < 32; ++tpl){
        int tp = pt*32 + tpl;
        float acc = sv;
        #pragma unroll
        for (int g = 0; g < 8; ++g){
            float4 ep = *(const float4*)&eps[tpl][dg*36 + 4*g];
            float da = fmaf(ep.x, eq[4*g+0], 1.0f);
            float db = fmaf(ep.y, eq[4*g+1], 1.0f);
            float dc = fmaf(ep.z, eq[4*g+2], 1.0f);
            float dd = fmaf(ep.w, eq[4*g+3], 1.0f);
            float dab = da * db;
            float dcd = dc * dd;
            float nab = fmaf(vm2[4*g+1], da, vm2[4*g+0] * db);
            float ncd = fmaf(vm2[4*g+3], dc, vm2[4*g+2] * dd);
            float num = fmaf(ncd, dab, nab * dcd);
            acc = fmaf(num, __builtin_amdgcn_rcpf(dab * dcd), acc);
        }
        acc += __shfl_xor(acc, 1);
        acc += __shfl_xor(acc, 2);
        acc += __shfl_xor(acc, 4);
        if (dg == 0 && tp < t){
            Wx[((size_t)(b*T_ + t))*T_ + tp] = f2bf(__expf(acc));
        }
    }
}

// ---------------------------------------------------------------------------
// K6: ctx[b][t][d] = (sum_t' Wx[b][t][t'] * h[t'][d]) / l[b][t]; t=0 -> h[0].
// TRIANGULAR K-loop (kk <= m0). No memset / no l buffer:
//  (a) diagonal tile (kk == m0) masked during As staging (tp >= t -> 0);
//  (b) row sums accumulated from staged post-mask values, 8-lane shfl-
//      reduced into LDS (same bf16 values, different fp32 sum order).
// ---------------------------------------------------------------------------
__global__ __launch_bounds__(256) void k_ctx(const u16* __restrict__ Wx,
                                             u16* __restrict__ HC){
    __shared__ u16 As[64][88];
    __shared__ u16 Ws[64][88];
    __shared__ float rs[64];
    int tid  = threadIdx.x;
    int lane = tid & 63;
    int w    = tid >> 6;
    int col  = lane & 15;
    int quad = lane >> 4;
    int b    = blockIdx.y;
    int m0   = (blockIdx.x >> 2) * 64;   // t tile
    int n0   = (blockIdx.x & 3) * 64;    // d tile

    const u16* A = Wx + (size_t)b * T_ * T_;

    int r0 = tid >> 3;                   // As row for i=0 (i=1: r0+32)
    int c8 = (tid & 7) * 8;
    float rsum0 = 0.0f, rsum1 = 0.0f;

    f32x4 acc[4];
    #pragma unroll
    for (int nt = 0; nt < 4; ++nt)
        #pragma unroll
        for (int r = 0; r < 4; ++r) acc[nt][r] = 0.0f;

    int kmax = m0 + 64;                  // strictly-past columns only
    for (int kk = 0; kk < kmax; kk += 64){
        bool diag = (kk == m0);
        #pragma unroll
        for (int i = 0; i < 2; ++i){
            int r = r0 + i*32;
            s16x8 v = *(const s16x8*)&A[(size_t)(m0 + r)*T_ + kk + c8];
            if (diag){
                #pragma unroll
                for (int j = 0; j < 8; ++j)
                    if (c8 + j >= r) v[j] = 0;   // tp >= t -> zero
            }
            *(s16x8*)&As[r][c8] = v;
            float s = 0.0f;
            #pragma unroll
            for (int j = 0; j < 8; ++j) s += bf2f((u16)v[j]);
            if (i == 0) rsum0 += s; else rsum1 += s;
        }
        #pragma unroll
        for (int i = 0; i < 8; ++i){
            int idx = tid + i*256;
            int k   = idx >> 5;
            int n2  = (idx & 31) * 2;
            u16x2 v2 = *(const u16x2*)&HC[((size_t)((kk + k)*B_ + b))*D2_ + n0 + n2];
            Ws[n2][k]   = v2.x;
            Ws[n2+1][k] = v2.y;
        }
        barrier_lgkm();
        #pragma unroll
        for (int ks = 0; ks < 2; ++ks){
            s16x8 a = *(const s16x8*)&As[w*16 + col][ks*32 + quad*8];
            #pragma unroll
            for (int nt = 0; nt < 4; ++nt){
                s16x8 bb = *(const s16x8*)&Ws[nt*16 + col][ks*32 + quad*8];
                acc[nt] = __builtin_amdgcn_mfma_f32_16x16x32_bf16(a, bb, acc[nt], 0, 0, 0);
            }
        }
        barrier_lgkm();
    }

    // row sums: reduce across the 8 threads sharing each As row
    rsum0 += __shfl_xor(rsum0, 1); rsum0 += __shfl_xor(rsum0, 2); rsum0 += __shfl_xor(rsum0, 4);
    rsum1 += __shfl_xor(rsum1, 1); rsum1 += __shfl_xor(rsum1, 2); rsum1 += __shfl_xor(rsum1, 4);
    if ((tid & 7) == 0){ rs[r0] = rsum0; rs[r0 + 32] = rsum1; }
    barrier_lgkm();

    float linv[4];
    #pragma unroll
    for (int r = 0; r < 4; ++r){
        int rr = w*16 + quad*4 + r;          // t - m0
        float lv = (m0 + rr > 0) ? rs[rr] : 1.0f;
        linv[r] = 1.0f / lv;
    }
    #pragma unroll
    for (int nt = 0; nt < 4; ++nt){
        int n = n0 + nt*16 + col;
        #pragma unroll
        for (int r = 0; r < 4; ++r){
            int t = m0 + w*16 + quad*4 + r;
            u16 ov;
            if (t == 0) ov = HC[(size_t)b*D2_ + n];          // ctx(0) = h(0)
            else        ov = f2bf(acc[nt][r] * linv[r]);
            HC[((size_t)(t*B_ + b))*D2_ + D_ + n] = ov;
        }
    }
}

// ---------------------------------------------------------------------------
extern "C" void kernel_launch(void* const* d_in, const int* in_sizes, int n_in,
                              void* d_out, int out_size, void* d_ws, size_t ws_size,
                              hipStream_t stream){
    const int*   x     = (const int*)d_in[0];
    const float* embed = (const float*)d_in[1];
    const float* W_ih  = (const float*)d_in[2];
    const float* W_hh  = (const float*)d_in[3];
    const float* b_h   = (const float*)d_in[4];
    const float* W_att = (const float*)d_in[5];
    const float* U_att = (const float*)d_in[6];
    const float* v_att = (const float*)d_in[7];
    const float* fc_W  = (const float*)d_in[8];
    const float* fc_b  = (const float*)d_in[9];

    char* ws = (char*)d_ws;
    float* EW   = (float*)ws;                       // 512 KB (dead after k_gather)
    u16*   Wab  = (u16*)(ws + 524288);              // 128 KB bf16 W_att^T
    u16*   Uab  = (u16*)(ws + 655360);              // 128 KB bf16 U_att^T (contig)
    u16*   fcWb = (u16*)(ws + 786432);              // 512 KB bf16 fc_W^T
    u16*   HC   = (u16*)(ws + 1310720);             // 32 MB  [h|ctx] bf16
    u16*   EP   = (u16*)(ws + 34865152);            // 16 MB  exp(2*P) bf16
    u16*   EQ   = (u16*)(ws + 51642368);            // 16 MB  exp(2*Q) bf16 (EP+32768*256)
    float* XP   = (float*)(ws + 34865152);          // 32 MB  fp32, ALIASES EP+EQ (dead after k_rnn)
    u16*   Wx   = (u16*)d_out;                      // 33.5 MB scratch in d_out (dead until fc)

    k_ew_cvt<<<dim3(2048),        dim3(256), 0, stream>>>(embed, W_ih, b_h, EW,
                                                          W_att, U_att, fc_W,
                                                          Wab, Uab, fcWb);
    k_gather<<<dim3(T_*B_/4),     dim3(256), 0, stream>>>(x, EW, XP);
    k_rnn   <<<dim3(16),          dim3(512), 0, stream>>>(XP, W_hh, HC);
    // merged P/Q projection: one GEMM over [Wab|Uab], A staged once
    k_gemm  <<<dim3(512, 8),      dim3(256), 0, stream>>>(HC, D2_, Wab, nullptr, (void*)EP, D_, D2_, 3);
    k_energy<<<dim3(B_*136),      dim3(256), 0, stream>>>(EP, EQ, v_att, Wx);
    k_ctx   <<<dim3(32, B_),      dim3(256), 0, stream>>>(Wx, HC);
    k_fc    <<<dim3(256, 4),      dim3(512), 0, stream>>>(HC, fcWb, fc_b, (float*)d_out);
}